// Round 1
// baseline (641.859 us; speedup 1.0000x reference)
//
#include <hip/hip_runtime.h>
#include <hip/hip_bf16.h>
#include <math.h>

// ---------------------------------------------------------------------------
// GCN 2-layer forward:
//   h1 = leaky_relu( D^-1/2 (A+I) D^-1/2 (x@W1) + b1 )
//   out = softmax( D^-1/2 (A+I) D^-1/2 (h1@W2) + b2 )
// Factorization: hs = (x@W)*dinv;  out[v] = dinv[v]*(sum_{src->v} hs[src] + hs[v]) + b
// Pipeline: detect idx width -> count deg -> exclusive scan (CSR) -> scatter src
//           -> gemm1(+dinv scale) -> agg1(+bias+leakyrelu) -> gemm2(+dinv scale)
//           -> agg2(+bias+softmax)
// ---------------------------------------------------------------------------

#define WAVE 64

// --- edge index accessor: harness may ship int64 or int32 (jax x64 ambiguity)
__device__ __forceinline__ int edge_val(const void* ep, size_t idx, int is64) {
    if (is64) return (int)(((const long long*)ep)[idx]);
    return ((const int*)ep)[idx];
}

// Detect whether edge buffer is int64: high 32-bit words of first 64 elements
// are all zero only for int64 (values < 1e5; int32 odd words are random ids).
__global__ void detect_width(const unsigned int* __restrict__ ew, int* __restrict__ flag) {
    if (threadIdx.x == 0 && blockIdx.x == 0) {
        int f = 1;
        for (int i = 0; i < 64; ++i)
            if (ew[2 * i + 1] != 0u) { f = 0; break; }
        *flag = f;
    }
}

__global__ void count_deg(const void* __restrict__ edges, int* __restrict__ deg,
                          int E, const int* __restrict__ flagp) {
    const int is64 = *flagp;
    int i = blockIdx.x * 256 + threadIdx.x;
    const int stride = gridDim.x * 256;
    for (; i < E; i += stride) {
        int d = edge_val(edges, (size_t)E + i, is64);  // dst row
        atomicAdd(&deg[d], 1);
    }
}

// exclusive scan, 3 kernels. scan1: per-block (1024 elems) local exclusive scan
__global__ void scan1(const int* __restrict__ deg, int* __restrict__ row_ptr,
                      int* __restrict__ blk, int n) {
    __shared__ int sm[256];
    const int tid = threadIdx.x;
    const int base = blockIdx.x * 1024 + tid * 4;
    int v[4];
#pragma unroll
    for (int i = 0; i < 4; ++i) v[i] = (base + i < n) ? deg[base + i] : 0;
    const int t = v[0] + v[1] + v[2] + v[3];
    sm[tid] = t;
    __syncthreads();
    for (int off = 1; off < 256; off <<= 1) {
        int val = (tid >= off) ? sm[tid - off] : 0;
        __syncthreads();
        sm[tid] += val;
        __syncthreads();
    }
    int run = sm[tid] - t;  // exclusive within block
#pragma unroll
    for (int i = 0; i < 4; ++i) {
        if (base + i < n) row_ptr[base + i] = run;
        run += v[i];
    }
    if (tid == 255) blk[blockIdx.x] = sm[255];
}

__global__ void scan2(int* __restrict__ blk, int nb) {
    __shared__ int sm[256];
    const int tid = threadIdx.x;
    const int t = (tid < nb) ? blk[tid] : 0;
    sm[tid] = t;
    __syncthreads();
    for (int off = 1; off < 256; off <<= 1) {
        int val = (tid >= off) ? sm[tid - off] : 0;
        __syncthreads();
        sm[tid] += val;
        __syncthreads();
    }
    if (tid < nb) blk[tid] = sm[tid] - t;  // exclusive block offsets
}

__global__ void scan3(int* __restrict__ row_ptr, int* __restrict__ fill,
                      float* __restrict__ dinv, const int* __restrict__ deg,
                      const int* __restrict__ blk, int n, int E) {
    const int i = blockIdx.x * 256 + threadIdx.x;
    if (i < n) {
        const int v = row_ptr[i] + blk[i >> 10];
        row_ptr[i] = v;
        fill[i] = v;
        dinv[i] = rsqrtf((float)deg[i] + 1.0f);
    }
    if (i == 0) row_ptr[n] = E;
}

__global__ void scatter_edges(const void* __restrict__ edges, int* __restrict__ fill,
                              int* __restrict__ col_src, int E, const int* __restrict__ flagp) {
    const int is64 = *flagp;
    int i = blockIdx.x * 256 + threadIdx.x;
    const int stride = gridDim.x * 256;
    for (; i < E; i += stride) {
        const int d = edge_val(edges, (size_t)E + i, is64);
        const int s = edge_val(edges, (size_t)i, is64);
        const int pos = atomicAdd(&fill[d], 1);
        col_src[pos] = s;
    }
}

// GEMM1: hs1[v][c] = (sum_k x[v][k]*W1[k][c]) * dinv[v]   (256 -> 64)
// block = 128 threads (16 col-grp x 8 row-grp), 32 rows/block, thread = 4r x 4c,
// k tiled in two halves of 128 to keep static LDS under 64KB.
__global__ __launch_bounds__(128) void gemm1_kernel(
    const float* __restrict__ x, const float* __restrict__ W1,
    const float* __restrict__ dinv, float* __restrict__ hs1, int n) {
    __shared__ float xs[32 * 132];   // 32 rows x 128 k (+4 pad)
    __shared__ float wl[128 * 64];   // k-half x 64 cols
    const int tid = threadIdx.x;
    const int tj = tid & 15;   // col group (4 cols)
    const int ti = tid >> 4;   // row group (4 rows), 0..7
    const int row0 = blockIdx.x * 32;
    float acc[4][4] = {};

    for (int kt = 0; kt < 2; ++kt) {
        // stage W half: 8192 floats = 2048 float4, 16 per thread
        const float4* wsrc = (const float4*)(W1 + kt * 128 * 64);
        float4* wdst = (float4*)wl;
#pragma unroll
        for (int i = 0; i < 16; ++i) wdst[tid + 128 * i] = wsrc[tid + 128 * i];
        // stage x: 32 rows x 128 floats = 1024 float4, 8 per thread
#pragma unroll
        for (int i = 0; i < 8; ++i) {
            const int flat = tid + 128 * i;
            const int r = flat >> 5;        // row 0..31
            const int c4 = flat & 31;       // float4 within 128-k window
            int gr = row0 + r;
            if (gr >= n) gr = n - 1;
            float4 v = *(const float4*)(x + (size_t)gr * 256 + kt * 128 + c4 * 4);
            *(float4*)(xs + r * 132 + c4 * 4) = v;
        }
        __syncthreads();
#pragma unroll 4
        for (int k = 0; k < 128; ++k) {
            const float4 wv = *(const float4*)(wl + k * 64 + tj * 4);
            float xv[4];
#pragma unroll
            for (int j = 0; j < 4; ++j) xv[j] = xs[(ti * 4 + j) * 132 + k];
#pragma unroll
            for (int j = 0; j < 4; ++j) {
                acc[j][0] += xv[j] * wv.x;
                acc[j][1] += xv[j] * wv.y;
                acc[j][2] += xv[j] * wv.z;
                acc[j][3] += xv[j] * wv.w;
            }
        }
        __syncthreads();
    }
#pragma unroll
    for (int j = 0; j < 4; ++j) {
        const int gr = row0 + ti * 4 + j;
        if (gr < n) {
            const float dv = dinv[gr];
            float4 o;
            o.x = acc[j][0] * dv; o.y = acc[j][1] * dv;
            o.z = acc[j][2] * dv; o.w = acc[j][3] * dv;
            *(float4*)(hs1 + (size_t)gr * 64 + tj * 4) = o;
        }
    }
}

// AGG1: out1[v][c] = leakyrelu( dinv[v]*(sum_in hs1[src][c] + hs1[v][c]) + b1[c] )
// one wave per node, lane = column (64)
__global__ __launch_bounds__(256) void agg1_kernel(
    const int* __restrict__ row_ptr, const int* __restrict__ col_src,
    const float* __restrict__ hs1, const float* __restrict__ dinv,
    const float* __restrict__ b1, float* __restrict__ out1, int n) {
    const int lane = threadIdx.x & 63;
    int v = blockIdx.x * 4 + (threadIdx.x >> 6);
    v = __builtin_amdgcn_readfirstlane(v);  // force wave-uniform -> scalar loads
    if (v >= n) return;
    const int rs = row_ptr[v];
    const int re = row_ptr[v + 1];
    float a0 = 0.f, a1 = 0.f, a2 = 0.f, a3 = 0.f;
    int e = rs;
    for (; e + 4 <= re; e += 4) {
        const int s0 = col_src[e], s1 = col_src[e + 1], s2 = col_src[e + 2], s3 = col_src[e + 3];
        a0 += hs1[(size_t)s0 * 64 + lane];
        a1 += hs1[(size_t)s1 * 64 + lane];
        a2 += hs1[(size_t)s2 * 64 + lane];
        a3 += hs1[(size_t)s3 * 64 + lane];
    }
    for (; e < re; ++e) a0 += hs1[(size_t)col_src[e] * 64 + lane];
    const float acc = (a0 + a1) + (a2 + a3);
    const float res = dinv[v] * (acc + hs1[(size_t)v * 64 + lane]) + b1[lane];
    out1[(size_t)v * 64 + lane] = res > 0.f ? res : 0.01f * res;
}

// GEMM2: hs2[v][c] = (sum_k out1[v][k]*W2[k][c]) * dinv[v]   (64 -> 4)
__global__ __launch_bounds__(256) void gemm2_kernel(
    const float* __restrict__ out1, const float* __restrict__ W2,
    const float* __restrict__ dinv, float* __restrict__ hs2, int n) {
    __shared__ float4 wl[64];  // W2 row k as float4 (4 cols)
    const int tid = threadIdx.x;
    if (tid < 64) wl[tid] = *(const float4*)(W2 + tid * 4);
    __syncthreads();
    const int row = blockIdx.x * 256 + tid;
    if (row >= n) return;
    const float4* xr = (const float4*)(out1 + (size_t)row * 64);
    float ax = 0.f, ay = 0.f, az = 0.f, aw = 0.f;
#pragma unroll
    for (int k4 = 0; k4 < 16; ++k4) {
        const float4 xv = xr[k4];
        const float4 w0 = wl[k4 * 4 + 0], w1 = wl[k4 * 4 + 1];
        const float4 w2 = wl[k4 * 4 + 2], w3 = wl[k4 * 4 + 3];
        ax += xv.x * w0.x + xv.y * w1.x + xv.z * w2.x + xv.w * w3.x;
        ay += xv.x * w0.y + xv.y * w1.y + xv.z * w2.y + xv.w * w3.y;
        az += xv.x * w0.z + xv.y * w1.z + xv.z * w2.z + xv.w * w3.z;
        aw += xv.x * w0.w + xv.y * w1.w + xv.z * w2.w + xv.w * w3.w;
    }
    const float dv = dinv[row];
    float4 o; o.x = ax * dv; o.y = ay * dv; o.z = az * dv; o.w = aw * dv;
    *(float4*)(hs2 + (size_t)row * 4) = o;
}

// AGG2 + softmax: wave per node; lane -> (edge slot = lane>>2, col = lane&3)
__global__ __launch_bounds__(256) void agg2_kernel(
    const int* __restrict__ row_ptr, const int* __restrict__ col_src,
    const float* __restrict__ hs2, const float* __restrict__ dinv,
    const float* __restrict__ b2, float* __restrict__ out, int n) {
    const int lane = threadIdx.x & 63;
    int v = blockIdx.x * 4 + (threadIdx.x >> 6);
    v = __builtin_amdgcn_readfirstlane(v);
    if (v >= n) return;
    const int c = lane & 3;
    const int ei = lane >> 2;
    const int rs = row_ptr[v];
    const int re = row_ptr[v + 1];
    float acc = 0.f;
    for (int e0 = rs; e0 < re; e0 += 16) {
        const int e = e0 + ei;
        if (e < re) {
            const int s = col_src[e];
            acc += hs2[(size_t)s * 4 + c];
        }
    }
    acc += __shfl_xor(acc, 4);
    acc += __shfl_xor(acc, 8);
    acc += __shfl_xor(acc, 16);
    acc += __shfl_xor(acc, 32);
    const float val = dinv[v] * (acc + hs2[(size_t)v * 4 + c]) + b2[c];
    float m = fmaxf(val, __shfl_xor(val, 1));
    m = fmaxf(m, __shfl_xor(m, 2));
    const float ex = __expf(val - m);
    float s = ex + __shfl_xor(ex, 1);
    s += __shfl_xor(s, 2);
    if (lane < 4) out[(size_t)v * 4 + c] = ex / s;
}

extern "C" void kernel_launch(void* const* d_in, const int* in_sizes, int n_in,
                              void* d_out, int out_size, void* d_ws, size_t ws_size,
                              hipStream_t stream) {
    const float* x  = (const float*)d_in[0];
    const void*  ei = d_in[1];
    const float* W1 = (const float*)d_in[2];
    const float* b1 = (const float*)d_in[3];
    const float* W2 = (const float*)d_in[4];
    const float* b2 = (const float*)d_in[5];
    const int n = in_sizes[0] / 256;
    const int E = in_sizes[1] / 2;

    char* ws = (char*)d_ws;
    size_t off = 0;
    auto alloc = [&](size_t bytes) -> void* {
        void* p = ws + off;
        off += (bytes + 255) & ~(size_t)255;
        return p;
    };
    int*   deg     = (int*)alloc(sizeof(int) * n);
    int*   row_ptr = (int*)alloc(sizeof(int) * (n + 1));
    int*   fill    = (int*)alloc(sizeof(int) * n);
    int*   blk     = (int*)alloc(sizeof(int) * 256);
    int*   flag    = (int*)alloc(sizeof(int) * 64);
    int*   col_src = (int*)alloc(sizeof(int) * (size_t)E);
    float* dinv    = (float*)alloc(sizeof(float) * n);
    float* hs1     = (float*)alloc(sizeof(float) * (size_t)n * 64);
    float* out1    = (float*)alloc(sizeof(float) * (size_t)n * 64);
    float* hs2     = (float*)alloc(sizeof(float) * (size_t)n * 4);
    (void)ws_size; (void)n_in; (void)out_size;

    hipMemsetAsync(deg, 0, sizeof(int) * n, stream);
    detect_width<<<1, 64, 0, stream>>>((const unsigned int*)ei, flag);
    count_deg<<<2048, 256, 0, stream>>>(ei, deg, E, flag);
    const int nb = (n + 1023) / 1024;
    scan1<<<nb, 256, 0, stream>>>(deg, row_ptr, blk, n);
    scan2<<<1, 256, 0, stream>>>(blk, nb);
    scan3<<<(n + 255) / 256, 256, 0, stream>>>(row_ptr, fill, dinv, deg, blk, n, E);
    scatter_edges<<<2048, 256, 0, stream>>>(ei, fill, col_src, E, flag);
    gemm1_kernel<<<(n + 31) / 32, 128, 0, stream>>>(x, W1, dinv, hs1, n);
    agg1_kernel<<<(n + 3) / 4, 256, 0, stream>>>(row_ptr, col_src, hs1, dinv, b1, out1, n);
    gemm2_kernel<<<(n + 255) / 256, 256, 0, stream>>>(out1, W2, dinv, hs2, n);
    agg2_kernel<<<(n + 3) / 4, 256, 0, stream>>>(row_ptr, col_src, hs2, dinv, b2, (float*)d_out, n);
}